// Round 1
// baseline (1393.424 us; speedup 1.0000x reference)
//
#include <hip/hip_runtime.h>

#define N_NODES 100000
#define N_EDGES 3200000
#define IN_DIM 128
#define HID 64
#define NUM_GRAPHS 512
#define NUM_CLASSES 10

// ---------------- CSR build ----------------

__global__ __launch_bounds__(256) void count_deg_kernel(const int* __restrict__ dst,
                                                        int* __restrict__ deg) {
  for (int e = blockIdx.x * blockDim.x + threadIdx.x; e < N_EDGES;
       e += gridDim.x * blockDim.x)
    atomicAdd(&deg[dst[e]], 1);
}

__global__ __launch_bounds__(256) void dinv_kernel(const int* __restrict__ deg,
                                                   float* __restrict__ dinv) {
  int i = blockIdx.x * blockDim.x + threadIdx.x;
  if (i < N_NODES) dinv[i] = rsqrtf((float)(deg[i] + 1));
}

// block-level exclusive scan (1024 elems/block), local results + block sums
__global__ __launch_bounds__(1024) void scan_block_kernel(const int* __restrict__ in,
                                                          int* __restrict__ out,
                                                          int* __restrict__ blk_sums,
                                                          int n) {
  int tid = threadIdx.x;
  int gid = blockIdx.x * 1024 + tid;
  int v = (gid < n) ? in[gid] : 0;
  int lane = tid & 63, wid = tid >> 6;
  int x = v;
#pragma unroll
  for (int off = 1; off < 64; off <<= 1) {
    int t = __shfl_up(x, off);
    if (lane >= off) x += t;
  }
  __shared__ int wsum[16];
  if (lane == 63) wsum[wid] = x;
  __syncthreads();
  if (wid == 0) {
    int s = (lane < 16) ? wsum[lane] : 0;
#pragma unroll
    for (int off = 1; off < 16; off <<= 1) {
      int t = __shfl_up(s, off);
      if (lane >= off) s += t;
    }
    if (lane < 16) wsum[lane] = s;
  }
  __syncthreads();
  int base = (wid > 0) ? wsum[wid - 1] : 0;
  int incl = x + base;
  if (gid < n) out[gid] = incl - v;  // exclusive within block
  if (tid == 1023) blk_sums[blockIdx.x] = incl;
}

// single-wave scan of block sums -> exclusive offsets; blk_off[nb] = total
__global__ __launch_bounds__(64) void scan_sums_kernel(const int* __restrict__ blk_sums,
                                                       int* __restrict__ blk_off, int nb) {
  int lane = threadIdx.x;
  int carry = 0;
  for (int base = 0; base < nb; base += 64) {
    int i = base + lane;
    int v = (i < nb) ? blk_sums[i] : 0;
    int x = v;
#pragma unroll
    for (int off = 1; off < 64; off <<= 1) {
      int t = __shfl_up(x, off);
      if (lane >= off) x += t;
    }
    if (i < nb) blk_off[i] = carry + x - v;
    carry += __shfl(x, 63);
  }
  if (lane == 0) blk_off[nb] = carry;
}

__global__ __launch_bounds__(256) void add_offsets_kernel(int* __restrict__ row_ptr,
                                                          int* __restrict__ cursor,
                                                          const int* __restrict__ blk_off,
                                                          int n, int nb) {
  int i = blockIdx.x * blockDim.x + threadIdx.x;
  if (i < n) {
    int r = row_ptr[i] + blk_off[i >> 10];
    row_ptr[i] = r;
    cursor[i] = r;
  }
  if (i == 0) row_ptr[n] = blk_off[nb];
}

__global__ __launch_bounds__(256) void fill_kernel(const int* __restrict__ src,
                                                   const int* __restrict__ dst,
                                                   int* __restrict__ cursor,
                                                   int* __restrict__ csr_src) {
  for (int e = blockIdx.x * blockDim.x + threadIdx.x; e < N_EDGES;
       e += gridDim.x * blockDim.x) {
    int d = dst[e];
    int pos = atomicAdd(&cursor[d], 1);
    csr_src[pos] = src[e];
  }
}

// ---------------- GEMM: out[n][64] = A[n][K] @ W[K][64] ----------------
// 64x64 tile per block, 256 threads, 4x4 register tile, K staged in 64-chunks.
template <int K>
__global__ __launch_bounds__(256) void gemm_kernel(const float* __restrict__ A,
                                                   const float* __restrict__ W,
                                                   float* __restrict__ out, int n) {
  __shared__ float As[64][68];  // pad 68 to break bank alignment
  __shared__ float Ws[64][64];
  int tid = threadIdx.x;
  int row0 = blockIdx.x * 64;
  int tx = tid & 15, ty = tid >> 4;  // tx -> j group, ty -> row group
  float acc[4][4] = {};
  for (int k0 = 0; k0 < K; k0 += 64) {
    for (int idx = tid * 4; idx < 64 * 64; idx += 1024) {
      int r = idx >> 6, c = idx & 63;
      float4 v = make_float4(0.f, 0.f, 0.f, 0.f);
      if (row0 + r < n)
        v = *(const float4*)&A[(size_t)(row0 + r) * K + k0 + c];
      *(float4*)&As[r][c] = v;
    }
    for (int idx = tid * 4; idx < 64 * 64; idx += 1024) {
      int r = idx >> 6, c = idx & 63;
      *(float4*)&Ws[r][c] = *(const float4*)&W[(size_t)(k0 + r) * 64 + c];
    }
    __syncthreads();
#pragma unroll
    for (int k = 0; k < 64; k += 4) {
      float av[4][4], wv[4][4];
#pragma unroll
      for (int i = 0; i < 4; ++i)
        *(float4*)&av[i][0] = *(float4*)&As[ty * 4 + i][k];  // av[i][kk]
#pragma unroll
      for (int kk = 0; kk < 4; ++kk)
        *(float4*)&wv[kk][0] = *(float4*)&Ws[k + kk][tx * 4];  // wv[kk][j]
#pragma unroll
      for (int kk = 0; kk < 4; ++kk)
#pragma unroll
        for (int i = 0; i < 4; ++i)
#pragma unroll
          for (int j = 0; j < 4; ++j)
            acc[i][j] += av[i][kk] * wv[kk][j];
    }
    __syncthreads();
  }
#pragma unroll
  for (int i = 0; i < 4; ++i) {
    int row = row0 + ty * 4 + i;
    if (row < n) {
      float4 v = make_float4(acc[i][0], acc[i][1], acc[i][2], acc[i][3]);
      *(float4*)&out[(size_t)row * 64 + tx * 4] = v;
    }
  }
}

// ---------------- Aggregate: wave per node, lane per dim ----------------
__global__ __launch_bounds__(256) void aggregate_kernel(
    const float* __restrict__ h, const int* __restrict__ row_ptr,
    const int* __restrict__ csr_src, const float* __restrict__ dinv,
    const float* __restrict__ bias, float* __restrict__ out, int relu) {
  int node = blockIdx.x * 4 + (threadIdx.x >> 6);
  if (node >= N_NODES) return;
  int lane = threadIdx.x & 63;
  int beg = row_ptr[node], end = row_ptr[node + 1];
  float di = dinv[node];
  float acc = h[(size_t)node * HID + lane] * di;  // self loop (x di again below)
  for (int e = beg; e < end; ++e) {
    int s = csr_src[e];
    acc += h[(size_t)s * HID + lane] * dinv[s];
  }
  acc = acc * di + bias[lane];
  if (relu) acc = fmaxf(acc, 0.0f);
  out[(size_t)node * HID + lane] = acc;
}

// ---------------- Global mean pool (batch sorted) ----------------
__global__ __launch_bounds__(256) void pool_kernel(const float* __restrict__ h,
                                                   const int* __restrict__ batch,
                                                   float* __restrict__ pool,
                                                   int* __restrict__ cnt) {
  int waves = gridDim.x * (blockDim.x >> 6);
  int wave = blockIdx.x * (blockDim.x >> 6) + (threadIdx.x >> 6);
  int lane = threadIdx.x & 63;
  int chunk = (N_NODES + waves - 1) / waves;
  int n0 = wave * chunk;
  int n1 = min(n0 + chunk, N_NODES);
  if (n0 >= n1) return;
  int cur = batch[n0];
  float acc = 0.f;
  int c = 0;
  for (int nn = n0; nn < n1; ++nn) {
    int g = batch[nn];
    if (g != cur) {
      atomicAdd(&pool[(size_t)cur * HID + lane], acc);
      if (lane == 0) atomicAdd(&cnt[cur], c);
      acc = 0.f;
      c = 0;
      cur = g;
    }
    acc += h[(size_t)nn * HID + lane];
    ++c;
  }
  atomicAdd(&pool[(size_t)cur * HID + lane], acc);
  if (lane == 0) atomicAdd(&cnt[cur], c);
}

// ---------------- FC: [512,64] @ [64,10] + b ----------------
__global__ __launch_bounds__(64) void fc_kernel(const float* __restrict__ pool,
                                                const int* __restrict__ cnt,
                                                const float* __restrict__ Wfc,
                                                const float* __restrict__ bfc,
                                                float* __restrict__ out) {
  int g = blockIdx.x;
  int t = threadIdx.x;
  __shared__ float row[64];
  float inv = 1.0f / fmaxf((float)cnt[g], 1.0f);
  row[t] = pool[(size_t)g * HID + t] * inv;
  __syncthreads();
  if (t < NUM_CLASSES) {
    float acc = bfc[t];
#pragma unroll
    for (int k = 0; k < HID; ++k) acc += row[k] * Wfc[k * NUM_CLASSES + t];
    out[(size_t)g * NUM_CLASSES + t] = acc;
  }
}

// ---------------- launch ----------------
extern "C" void kernel_launch(void* const* d_in, const int* in_sizes, int n_in,
                              void* d_out, int out_size, void* d_ws, size_t ws_size,
                              hipStream_t stream) {
  const float* x = (const float*)d_in[0];
  const int* edge_index = (const int*)d_in[1];
  const int* batch = (const int*)d_in[2];
  const float* W1 = (const float*)d_in[3];
  const float* b1 = (const float*)d_in[4];
  const float* W2 = (const float*)d_in[5];
  const float* b2 = (const float*)d_in[6];
  const float* W3 = (const float*)d_in[7];
  const float* b3 = (const float*)d_in[8];
  const float* Wfc = (const float*)d_in[9];
  const float* bfc = (const float*)d_in[10];
  float* out = (float*)d_out;

  const int* src = edge_index;
  const int* dst = edge_index + N_EDGES;

  // workspace layout
  char* w = (char*)d_ws;
  float* h0 = (float*)w;                       // N*64 floats
  float* h1 = h0 + (size_t)N_NODES * HID;      // N*64 floats
  int* deg = (int*)(h1 + (size_t)N_NODES * HID);  // N ints (in-degree counts)
  float* dinv = (float*)(deg + N_NODES);       // N floats
  int* row_ptr = (int*)(dinv + N_NODES);       // N+1 ints
  int* cursor = row_ptr + (N_NODES + 1);       // N+1 ints
  int* blk_sums = cursor + (N_NODES + 1);      // 128 ints
  int* blk_off = blk_sums + 128;               // 128 ints
  int* csr_src = blk_off + 128;                // E ints
  float* pool = (float*)(csr_src + N_EDGES);   // 512*64 floats
  int* cnt = (int*)(pool + NUM_GRAPHS * HID);  // 512 ints

  hipMemsetAsync(deg, 0, N_NODES * sizeof(int), stream);
  hipMemsetAsync(pool, 0, NUM_GRAPHS * HID * sizeof(float), stream);
  hipMemsetAsync(cnt, 0, NUM_GRAPHS * sizeof(int), stream);

  // CSR build
  count_deg_kernel<<<2048, 256, 0, stream>>>(dst, deg);
  dinv_kernel<<<(N_NODES + 255) / 256, 256, 0, stream>>>(deg, dinv);
  const int nb = (N_NODES + 1023) / 1024;  // 98
  scan_block_kernel<<<nb, 1024, 0, stream>>>(deg, row_ptr, blk_sums, N_NODES);
  scan_sums_kernel<<<1, 64, 0, stream>>>(blk_sums, blk_off, nb);
  add_offsets_kernel<<<(N_NODES + 255) / 256, 256, 0, stream>>>(row_ptr, cursor,
                                                                blk_off, N_NODES, nb);
  fill_kernel<<<2048, 256, 0, stream>>>(src, dst, cursor, csr_src);

  const int ggrid = (N_NODES + 63) / 64;
  const int agrid = (N_NODES + 3) / 4;

  // layer 1
  gemm_kernel<IN_DIM><<<ggrid, 256, 0, stream>>>(x, W1, h0, N_NODES);
  aggregate_kernel<<<agrid, 256, 0, stream>>>(h0, row_ptr, csr_src, dinv, b1, h1, 1);
  // layer 2
  gemm_kernel<HID><<<ggrid, 256, 0, stream>>>(h1, W2, h0, N_NODES);
  aggregate_kernel<<<agrid, 256, 0, stream>>>(h0, row_ptr, csr_src, dinv, b2, h1, 1);
  // layer 3
  gemm_kernel<HID><<<ggrid, 256, 0, stream>>>(h1, W3, h0, N_NODES);
  aggregate_kernel<<<agrid, 256, 0, stream>>>(h0, row_ptr, csr_src, dinv, b3, h1, 0);

  // pool + fc
  pool_kernel<<<512, 256, 0, stream>>>(h1, batch, pool, cnt);
  fc_kernel<<<NUM_GRAPHS, 64, 0, stream>>>(pool, cnt, Wfc, bfc, out);
}

// Round 2
// 861.419 us; speedup vs baseline: 1.6176x; 1.6176x over previous
//
#include <hip/hip_runtime.h>

#define N_NODES 100000
#define N_EDGES 3200000
#define IN_DIM 128
#define HID 64
#define NUM_GRAPHS 512
#define NUM_CLASSES 10

// ---------------- CSR build ----------------

__global__ __launch_bounds__(256) void count_deg_kernel(const int* __restrict__ dst,
                                                        int* __restrict__ deg) {
  // int4 over 800000 vectors
  const int NV = N_EDGES / 4;
  for (int v = blockIdx.x * blockDim.x + threadIdx.x; v < NV;
       v += gridDim.x * blockDim.x) {
    int4 d = ((const int4*)dst)[v];
    atomicAdd(&deg[d.x], 1);
    atomicAdd(&deg[d.y], 1);
    atomicAdd(&deg[d.z], 1);
    atomicAdd(&deg[d.w], 1);
  }
}

__global__ __launch_bounds__(256) void dinv_kernel(const int* __restrict__ deg,
                                                   float* __restrict__ dinv) {
  int i = blockIdx.x * blockDim.x + threadIdx.x;
  if (i < N_NODES) dinv[i] = rsqrtf((float)(deg[i] + 1));
}

// block-level exclusive scan (1024 elems/block), local results + block sums
__global__ __launch_bounds__(1024) void scan_block_kernel(const int* __restrict__ in,
                                                          int* __restrict__ out,
                                                          int* __restrict__ blk_sums,
                                                          int n) {
  int tid = threadIdx.x;
  int gid = blockIdx.x * 1024 + tid;
  int v = (gid < n) ? in[gid] : 0;
  int lane = tid & 63, wid = tid >> 6;
  int x = v;
#pragma unroll
  for (int off = 1; off < 64; off <<= 1) {
    int t = __shfl_up(x, off);
    if (lane >= off) x += t;
  }
  __shared__ int wsum[16];
  if (lane == 63) wsum[wid] = x;
  __syncthreads();
  if (wid == 0) {
    int s = (lane < 16) ? wsum[lane] : 0;
#pragma unroll
    for (int off = 1; off < 16; off <<= 1) {
      int t = __shfl_up(s, off);
      if (lane >= off) s += t;
    }
    if (lane < 16) wsum[lane] = s;
  }
  __syncthreads();
  int base = (wid > 0) ? wsum[wid - 1] : 0;
  int incl = x + base;
  if (gid < n) out[gid] = incl - v;  // exclusive within block
  if (tid == 1023) blk_sums[blockIdx.x] = incl;
}

// single-wave scan of block sums -> exclusive offsets; blk_off[nb] = total
__global__ __launch_bounds__(64) void scan_sums_kernel(const int* __restrict__ blk_sums,
                                                       int* __restrict__ blk_off, int nb) {
  int lane = threadIdx.x;
  int carry = 0;
  for (int base = 0; base < nb; base += 64) {
    int i = base + lane;
    int v = (i < nb) ? blk_sums[i] : 0;
    int x = v;
#pragma unroll
    for (int off = 1; off < 64; off <<= 1) {
      int t = __shfl_up(x, off);
      if (lane >= off) x += t;
    }
    if (i < nb) blk_off[i] = carry + x - v;
    carry += __shfl(x, 63);
  }
  if (lane == 0) blk_off[nb] = carry;
}

__global__ __launch_bounds__(256) void add_offsets_kernel(int* __restrict__ row_ptr,
                                                          int* __restrict__ cursor,
                                                          const int* __restrict__ blk_off,
                                                          int n, int nb) {
  int i = blockIdx.x * blockDim.x + threadIdx.x;
  if (i < n) {
    int r = row_ptr[i] + blk_off[i >> 10];
    row_ptr[i] = r;
    cursor[i] = r;
  }
  if (i == 0) row_ptr[n] = blk_off[nb];
}

__global__ __launch_bounds__(256) void fill_kernel(const int* __restrict__ src,
                                                   const int* __restrict__ dst,
                                                   int* __restrict__ cursor,
                                                   int* __restrict__ csr_src) {
  const int NV = N_EDGES / 4;
  for (int v = blockIdx.x * blockDim.x + threadIdx.x; v < NV;
       v += gridDim.x * blockDim.x) {
    int4 s = ((const int4*)src)[v];
    int4 d = ((const int4*)dst)[v];
    csr_src[atomicAdd(&cursor[d.x], 1)] = s.x;
    csr_src[atomicAdd(&cursor[d.y], 1)] = s.y;
    csr_src[atomicAdd(&cursor[d.z], 1)] = s.z;
    csr_src[atomicAdd(&cursor[d.w], 1)] = s.w;
  }
}

// ---------------- GEMM: out[n][64] = (A[n][K] @ W[K][64]) * dinv[n] ----------------
// 64x64 tile per block, 256 threads, 4x4 register tile, K staged in 64-chunks.
template <int K>
__global__ __launch_bounds__(256) void gemm_kernel(const float* __restrict__ A,
                                                   const float* __restrict__ W,
                                                   const float* __restrict__ dinv,
                                                   float* __restrict__ out, int n) {
  __shared__ float As[64][68];  // pad to break bank alignment
  __shared__ float Ws[64][64];
  int tid = threadIdx.x;
  int row0 = blockIdx.x * 64;
  int tx = tid & 15, ty = tid >> 4;  // tx -> j group, ty -> row group
  float acc[4][4] = {};
  for (int k0 = 0; k0 < K; k0 += 64) {
    for (int idx = tid * 4; idx < 64 * 64; idx += 1024) {
      int r = idx >> 6, c = idx & 63;
      float4 v = make_float4(0.f, 0.f, 0.f, 0.f);
      if (row0 + r < n)
        v = *(const float4*)&A[(size_t)(row0 + r) * K + k0 + c];
      *(float4*)&As[r][c] = v;
    }
    for (int idx = tid * 4; idx < 64 * 64; idx += 1024) {
      int r = idx >> 6, c = idx & 63;
      *(float4*)&Ws[r][c] = *(const float4*)&W[(size_t)(k0 + r) * 64 + c];
    }
    __syncthreads();
#pragma unroll
    for (int k = 0; k < 64; k += 4) {
      float av[4][4], wv[4][4];
#pragma unroll
      for (int i = 0; i < 4; ++i)
        *(float4*)&av[i][0] = *(float4*)&As[ty * 4 + i][k];  // av[i][kk]
#pragma unroll
      for (int kk = 0; kk < 4; ++kk)
        *(float4*)&wv[kk][0] = *(float4*)&Ws[k + kk][tx * 4];  // wv[kk][j]
#pragma unroll
      for (int kk = 0; kk < 4; ++kk)
#pragma unroll
        for (int i = 0; i < 4; ++i)
#pragma unroll
          for (int j = 0; j < 4; ++j)
            acc[i][j] += av[i][kk] * wv[kk][j];
    }
    __syncthreads();
  }
#pragma unroll
  for (int i = 0; i < 4; ++i) {
    int row = row0 + ty * 4 + i;
    if (row < n) {
      float di = dinv[row];
      float4 v = make_float4(acc[i][0] * di, acc[i][1] * di, acc[i][2] * di,
                             acc[i][3] * di);
      *(float4*)&out[(size_t)row * 64 + tx * 4] = v;
    }
  }
}

// ---------------- Aggregate: wave per node, lane per dim ----------------
// hp is pre-scaled: hp[i] = (A@W)[i] * dinv[i].
// out[d] = relu?( dinv[d] * (hp[d] + sum_{s in N(d)} hp[s]) + bias )
__global__ __launch_bounds__(256) void aggregate_kernel(
    const float* __restrict__ hp, const int* __restrict__ row_ptr,
    const int* __restrict__ csr_src, const float* __restrict__ dinv,
    const float* __restrict__ bias, float* __restrict__ out, int relu) {
  int node = blockIdx.x * 4 + (threadIdx.x >> 6);
  if (node >= N_NODES) return;
  int lane = threadIdx.x & 63;
  int beg = row_ptr[node], end = row_ptr[node + 1];
  float acc = hp[(unsigned)(node * HID + lane)];  // self loop
  float acc2 = 0.f;
  int e = beg;
  for (; e + 8 <= end; e += 8) {
    int s0 = csr_src[e + 0];
    int s1 = csr_src[e + 1];
    int s2 = csr_src[e + 2];
    int s3 = csr_src[e + 3];
    int s4 = csr_src[e + 4];
    int s5 = csr_src[e + 5];
    int s6 = csr_src[e + 6];
    int s7 = csr_src[e + 7];
    float v0 = hp[(unsigned)(s0 * HID + lane)];
    float v1 = hp[(unsigned)(s1 * HID + lane)];
    float v2 = hp[(unsigned)(s2 * HID + lane)];
    float v3 = hp[(unsigned)(s3 * HID + lane)];
    float v4 = hp[(unsigned)(s4 * HID + lane)];
    float v5 = hp[(unsigned)(s5 * HID + lane)];
    float v6 = hp[(unsigned)(s6 * HID + lane)];
    float v7 = hp[(unsigned)(s7 * HID + lane)];
    acc += v0 + v1 + v2 + v3;
    acc2 += v4 + v5 + v6 + v7;
  }
  for (; e + 2 <= end; e += 2) {
    int s0 = csr_src[e + 0];
    int s1 = csr_src[e + 1];
    float v0 = hp[(unsigned)(s0 * HID + lane)];
    float v1 = hp[(unsigned)(s1 * HID + lane)];
    acc += v0;
    acc2 += v1;
  }
  if (e < end) acc += hp[(unsigned)(csr_src[e] * HID + lane)];
  acc = (acc + acc2) * dinv[node] + bias[lane];
  if (relu) acc = fmaxf(acc, 0.0f);
  out[(unsigned)(node * HID + lane)] = acc;
}

// ---------------- Global mean pool (batch sorted) ----------------
__global__ __launch_bounds__(256) void pool_kernel(const float* __restrict__ h,
                                                   const int* __restrict__ batch,
                                                   float* __restrict__ pool,
                                                   int* __restrict__ cnt) {
  int waves = gridDim.x * (blockDim.x >> 6);
  int wave = blockIdx.x * (blockDim.x >> 6) + (threadIdx.x >> 6);
  int lane = threadIdx.x & 63;
  int chunk = (N_NODES + waves - 1) / waves;
  int n0 = wave * chunk;
  int n1 = min(n0 + chunk, N_NODES);
  if (n0 >= n1) return;
  int cur = batch[n0];
  float acc = 0.f;
  int c = 0;
  for (int nn = n0; nn < n1; ++nn) {
    int g = batch[nn];
    if (g != cur) {
      atomicAdd(&pool[(size_t)cur * HID + lane], acc);
      if (lane == 0) atomicAdd(&cnt[cur], c);
      acc = 0.f;
      c = 0;
      cur = g;
    }
    acc += h[(size_t)nn * HID + lane];
    ++c;
  }
  atomicAdd(&pool[(size_t)cur * HID + lane], acc);
  if (lane == 0) atomicAdd(&cnt[cur], c);
}

// ---------------- FC: [512,64] @ [64,10] + b ----------------
__global__ __launch_bounds__(64) void fc_kernel(const float* __restrict__ pool,
                                                const int* __restrict__ cnt,
                                                const float* __restrict__ Wfc,
                                                const float* __restrict__ bfc,
                                                float* __restrict__ out) {
  int g = blockIdx.x;
  int t = threadIdx.x;
  __shared__ float row[64];
  float inv = 1.0f / fmaxf((float)cnt[g], 1.0f);
  row[t] = pool[(size_t)g * HID + t] * inv;
  __syncthreads();
  if (t < NUM_CLASSES) {
    float acc = bfc[t];
#pragma unroll
    for (int k = 0; k < HID; ++k) acc += row[k] * Wfc[k * NUM_CLASSES + t];
    out[(size_t)g * NUM_CLASSES + t] = acc;
  }
}

// ---------------- launch ----------------
extern "C" void kernel_launch(void* const* d_in, const int* in_sizes, int n_in,
                              void* d_out, int out_size, void* d_ws, size_t ws_size,
                              hipStream_t stream) {
  const float* x = (const float*)d_in[0];
  const int* edge_index = (const int*)d_in[1];
  const int* batch = (const int*)d_in[2];
  const float* W1 = (const float*)d_in[3];
  const float* b1 = (const float*)d_in[4];
  const float* W2 = (const float*)d_in[5];
  const float* b2 = (const float*)d_in[6];
  const float* W3 = (const float*)d_in[7];
  const float* b3 = (const float*)d_in[8];
  const float* Wfc = (const float*)d_in[9];
  const float* bfc = (const float*)d_in[10];
  float* out = (float*)d_out;

  const int* src = edge_index;
  const int* dst = edge_index + N_EDGES;

  // workspace layout
  char* w = (char*)d_ws;
  float* h0 = (float*)w;                          // N*64 floats
  float* h1 = h0 + (size_t)N_NODES * HID;         // N*64 floats
  int* deg = (int*)(h1 + (size_t)N_NODES * HID);  // N ints
  float* dinv = (float*)(deg + N_NODES);          // N floats
  int* row_ptr = (int*)(dinv + N_NODES);          // N+1 ints
  int* cursor = row_ptr + (N_NODES + 1);          // N+1 ints
  int* blk_sums = cursor + (N_NODES + 1);         // 128 ints
  int* blk_off = blk_sums + 128;                  // 128 ints
  int* csr_src = blk_off + 128;                   // E ints
  float* pool = (float*)(csr_src + N_EDGES);      // 512*64 floats
  int* cnt = (int*)(pool + NUM_GRAPHS * HID);     // 512 ints

  hipMemsetAsync(deg, 0, N_NODES * sizeof(int), stream);
  hipMemsetAsync(pool, 0, NUM_GRAPHS * HID * sizeof(float), stream);
  hipMemsetAsync(cnt, 0, NUM_GRAPHS * sizeof(int), stream);

  // CSR build
  count_deg_kernel<<<1024, 256, 0, stream>>>(dst, deg);
  dinv_kernel<<<(N_NODES + 255) / 256, 256, 0, stream>>>(deg, dinv);
  const int nb = (N_NODES + 1023) / 1024;  // 98
  scan_block_kernel<<<nb, 1024, 0, stream>>>(deg, row_ptr, blk_sums, N_NODES);
  scan_sums_kernel<<<1, 64, 0, stream>>>(blk_sums, blk_off, nb);
  add_offsets_kernel<<<(N_NODES + 255) / 256, 256, 0, stream>>>(row_ptr, cursor,
                                                                blk_off, N_NODES, nb);
  fill_kernel<<<1024, 256, 0, stream>>>(src, dst, cursor, csr_src);

  const int ggrid = (N_NODES + 63) / 64;
  const int agrid = (N_NODES + 3) / 4;

  // layer 1
  gemm_kernel<IN_DIM><<<ggrid, 256, 0, stream>>>(x, W1, dinv, h0, N_NODES);
  aggregate_kernel<<<agrid, 256, 0, stream>>>(h0, row_ptr, csr_src, dinv, b1, h1, 1);
  // layer 2
  gemm_kernel<HID><<<ggrid, 256, 0, stream>>>(h1, W2, dinv, h0, N_NODES);
  aggregate_kernel<<<agrid, 256, 0, stream>>>(h0, row_ptr, csr_src, dinv, b2, h1, 1);
  // layer 3
  gemm_kernel<HID><<<ggrid, 256, 0, stream>>>(h1, W3, dinv, h0, N_NODES);
  aggregate_kernel<<<agrid, 256, 0, stream>>>(h0, row_ptr, csr_src, dinv, b3, h1, 0);

  // pool + fc
  pool_kernel<<<512, 256, 0, stream>>>(h1, batch, pool, cnt);
  fc_kernel<<<NUM_GRAPHS, 64, 0, stream>>>(pool, cnt, Wfc, bfc, out);
}

// Round 3
// 594.298 us; speedup vs baseline: 2.3447x; 1.4495x over previous
//
#include <hip/hip_runtime.h>

#define N_NODES 100000
#define N_EDGES 3200000
#define IN_DIM 128
#define HID 64
#define NUM_GRAPHS 512
#define NUM_CLASSES 10

#define BSHIFT 7
#define BUCKET_W 128                              // nodes per bucket
#define NBUCKET ((N_NODES + BUCKET_W - 1) / BUCKET_W)  // 782

// ---------------- CSR build (bucketed, no per-edge global atomics) ----------

// k0: bucket-level histogram. Per-block LDS hist + aggregated global merge.
__global__ __launch_bounds__(256) void bucket_hist_kernel(const int* __restrict__ dst,
                                                          int* __restrict__ bucket_cnt) {
  __shared__ int h[NBUCKET];
  for (int i = threadIdx.x; i < NBUCKET; i += 256) h[i] = 0;
  __syncthreads();
  int chunk = (N_EDGES + gridDim.x - 1) / gridDim.x;
  int e0 = blockIdx.x * chunk, e1 = min(e0 + chunk, N_EDGES);
  for (int e = e0 + threadIdx.x; e < e1; e += 256)
    atomicAdd(&h[dst[e] >> BSHIFT], 1);
  __syncthreads();
  for (int i = threadIdx.x; i < NBUCKET; i += 256)
    if (h[i]) atomicAdd(&bucket_cnt[i], h[i]);
}

// k1: exclusive scan of bucket counts -> bucket_base/bucket_cursor; totals.
__global__ __launch_bounds__(64) void bucket_scan_kernel(const int* __restrict__ bucket_cnt,
                                                         int* __restrict__ bucket_base,
                                                         int* __restrict__ bucket_cursor,
                                                         int* __restrict__ row_ptr) {
  int lane = threadIdx.x;
  int carry = 0;
  for (int base = 0; base < NBUCKET; base += 64) {
    int i = base + lane;
    int v = (i < NBUCKET) ? bucket_cnt[i] : 0;
    int x = v;
#pragma unroll
    for (int off = 1; off < 64; off <<= 1) {
      int t = __shfl_up(x, off);
      if (lane >= off) x += t;
    }
    if (i < NBUCKET) {
      int ex = carry + x - v;
      bucket_base[i] = ex;
      bucket_cursor[i] = ex;
    }
    carry += __shfl(x, 63);
  }
  if (lane == 0) {
    bucket_base[NBUCKET] = carry;
    row_ptr[N_NODES] = carry;  // == N_EDGES
  }
}

// k2: scatter (src,dst) pairs into bucket-grouped pair_buf.
// Per-block LDS hist -> one global atomic per (block,bucket) to reserve a run.
__global__ __launch_bounds__(256) void pair_scatter_kernel(const int* __restrict__ src,
                                                           const int* __restrict__ dst,
                                                           int* __restrict__ bucket_cursor,
                                                           int2* __restrict__ pair_buf) {
  __shared__ int h[NBUCKET];
  for (int i = threadIdx.x; i < NBUCKET; i += 256) h[i] = 0;
  __syncthreads();
  int chunk = (N_EDGES + gridDim.x - 1) / gridDim.x;
  int e0 = blockIdx.x * chunk, e1 = min(e0 + chunk, N_EDGES);
  for (int e = e0 + threadIdx.x; e < e1; e += 256)
    atomicAdd(&h[dst[e] >> BSHIFT], 1);
  __syncthreads();
  for (int i = threadIdx.x; i < NBUCKET; i += 256) {
    int c = h[i];
    if (c) h[i] = atomicAdd(&bucket_cursor[i], c);
  }
  __syncthreads();
  for (int e = e0 + threadIdx.x; e < e1; e += 256) {
    int d = dst[e];
    int pos = atomicAdd(&h[d >> BSHIFT], 1);  // LDS atomic
    pair_buf[pos] = make_int2(src[e], d);
  }
}

// k3: one block per bucket. Per-node degree hist in LDS, in-LDS scan ->
// row_ptr + dinv, then csr fill with LDS-atomic cursors (stores stay in a
// 16KB window owned by this CU).
__global__ __launch_bounds__(256) void bucket_fill_kernel(const int2* __restrict__ pair_buf,
                                                          const int* __restrict__ bucket_base,
                                                          int* __restrict__ csr_src,
                                                          int* __restrict__ row_ptr,
                                                          float* __restrict__ dinv) {
  int b = blockIdx.x;
  int n0 = b << BSHIFT;
  int n1 = min(n0 + BUCKET_W, N_NODES);
  int nn = n1 - n0;
  int eb0 = bucket_base[b], eb1 = bucket_base[b + 1];
  __shared__ int hist[BUCKET_W];
  __shared__ int wtot[2];
  int tid = threadIdx.x;
  if (tid < BUCKET_W) hist[tid] = 0;
  __syncthreads();
  for (int e = eb0 + tid; e < eb1; e += 256)
    atomicAdd(&hist[pair_buf[e].y - n0], 1);
  __syncthreads();
  int v = 0, x = 0;
  if (tid < BUCKET_W) {
    v = hist[tid];
    x = v;
#pragma unroll
    for (int off = 1; off < 64; off <<= 1) {
      int t = __shfl_up(x, off);
      if ((tid & 63) >= off) x += t;
    }
    if ((tid & 63) == 63) wtot[tid >> 6] = x;
  }
  __syncthreads();
  if (tid < BUCKET_W) {
    int incl = x + ((tid >= 64) ? wtot[0] : 0);
    int base = eb0 + incl - v;  // exclusive
    if (tid < nn) {
      row_ptr[n0 + tid] = base;
      dinv[n0 + tid] = rsqrtf((float)(v + 1));
    }
    hist[tid] = base;  // becomes the cursor
  }
  __syncthreads();
  for (int e = eb0 + tid; e < eb1; e += 256) {
    int2 p = pair_buf[e];
    int pos = atomicAdd(&hist[p.y - n0], 1);  // LDS atomic
    csr_src[pos] = p.x;
  }
}

// ---------------- GEMM: out[n][64] = (A[n][K] @ W[K][64]) * dinv[n] --------
template <int K>
__global__ __launch_bounds__(256) void gemm_kernel(const float* __restrict__ A,
                                                   const float* __restrict__ W,
                                                   const float* __restrict__ dinv,
                                                   float* __restrict__ out, int n) {
  __shared__ float As[64][68];
  __shared__ float Ws[64][64];
  int tid = threadIdx.x;
  int row0 = blockIdx.x * 64;
  int tx = tid & 15, ty = tid >> 4;
  float acc[4][4] = {};
  for (int k0 = 0; k0 < K; k0 += 64) {
    for (int idx = tid * 4; idx < 64 * 64; idx += 1024) {
      int r = idx >> 6, c = idx & 63;
      float4 v = make_float4(0.f, 0.f, 0.f, 0.f);
      if (row0 + r < n)
        v = *(const float4*)&A[(size_t)(row0 + r) * K + k0 + c];
      *(float4*)&As[r][c] = v;
    }
    for (int idx = tid * 4; idx < 64 * 64; idx += 1024) {
      int r = idx >> 6, c = idx & 63;
      *(float4*)&Ws[r][c] = *(const float4*)&W[(size_t)(k0 + r) * 64 + c];
    }
    __syncthreads();
#pragma unroll
    for (int k = 0; k < 64; k += 4) {
      float av[4][4], wv[4][4];
#pragma unroll
      for (int i = 0; i < 4; ++i)
        *(float4*)&av[i][0] = *(float4*)&As[ty * 4 + i][k];
#pragma unroll
      for (int kk = 0; kk < 4; ++kk)
        *(float4*)&wv[kk][0] = *(float4*)&Ws[k + kk][tx * 4];
#pragma unroll
      for (int kk = 0; kk < 4; ++kk)
#pragma unroll
        for (int i = 0; i < 4; ++i)
#pragma unroll
          for (int j = 0; j < 4; ++j)
            acc[i][j] += av[i][kk] * wv[kk][j];
    }
    __syncthreads();
  }
#pragma unroll
  for (int i = 0; i < 4; ++i) {
    int row = row0 + ty * 4 + i;
    if (row < n) {
      float di = dinv[row];
      float4 v = make_float4(acc[i][0] * di, acc[i][1] * di, acc[i][2] * di,
                             acc[i][3] * di);
      *(float4*)&out[(size_t)row * 64 + tx * 4] = v;
    }
  }
}

// ---------------- Aggregate: wave per node, lane per dim --------------------
// hp pre-scaled by dinv. out[d] = relu?( dinv[d]*(hp[d]+sum hp[s]) + bias )
__global__ __launch_bounds__(256) void aggregate_kernel(
    const float* __restrict__ hp, const int* __restrict__ row_ptr,
    const int* __restrict__ csr_src, const float* __restrict__ dinv,
    const float* __restrict__ bias, float* __restrict__ out, int relu) {
  int node = blockIdx.x * 4 + (threadIdx.x >> 6);
  if (node >= N_NODES) return;
  int lane = threadIdx.x & 63;
  int beg = row_ptr[node], end = row_ptr[node + 1];
  float acc = hp[(unsigned)(node * HID + lane)];  // self loop
  float acc2 = 0.f;
  int e = beg;
  for (; e + 8 <= end; e += 8) {
    int s0 = csr_src[e + 0];
    int s1 = csr_src[e + 1];
    int s2 = csr_src[e + 2];
    int s3 = csr_src[e + 3];
    int s4 = csr_src[e + 4];
    int s5 = csr_src[e + 5];
    int s6 = csr_src[e + 6];
    int s7 = csr_src[e + 7];
    float v0 = hp[(unsigned)(s0 * HID + lane)];
    float v1 = hp[(unsigned)(s1 * HID + lane)];
    float v2 = hp[(unsigned)(s2 * HID + lane)];
    float v3 = hp[(unsigned)(s3 * HID + lane)];
    float v4 = hp[(unsigned)(s4 * HID + lane)];
    float v5 = hp[(unsigned)(s5 * HID + lane)];
    float v6 = hp[(unsigned)(s6 * HID + lane)];
    float v7 = hp[(unsigned)(s7 * HID + lane)];
    acc += v0 + v1 + v2 + v3;
    acc2 += v4 + v5 + v6 + v7;
  }
  for (; e + 2 <= end; e += 2) {
    int s0 = csr_src[e + 0];
    int s1 = csr_src[e + 1];
    acc += hp[(unsigned)(s0 * HID + lane)];
    acc2 += hp[(unsigned)(s1 * HID + lane)];
  }
  if (e < end) acc += hp[(unsigned)(csr_src[e] * HID + lane)];
  acc = (acc + acc2) * dinv[node] + bias[lane];
  if (relu) acc = fmaxf(acc, 0.0f);
  out[(unsigned)(node * HID + lane)] = acc;
}

// ---------------- Global mean pool (batch sorted) ---------------------------
__global__ __launch_bounds__(256) void pool_kernel(const float* __restrict__ h,
                                                   const int* __restrict__ batch,
                                                   float* __restrict__ pool,
                                                   int* __restrict__ cnt) {
  int waves = gridDim.x * (blockDim.x >> 6);
  int wave = blockIdx.x * (blockDim.x >> 6) + (threadIdx.x >> 6);
  int lane = threadIdx.x & 63;
  int chunk = (N_NODES + waves - 1) / waves;
  int n0 = wave * chunk;
  int n1 = min(n0 + chunk, N_NODES);
  if (n0 >= n1) return;
  int cur = batch[n0];
  float acc = 0.f;
  int c = 0;
  for (int nn = n0; nn < n1; ++nn) {
    int g = batch[nn];
    if (g != cur) {
      atomicAdd(&pool[(size_t)cur * HID + lane], acc);
      if (lane == 0) atomicAdd(&cnt[cur], c);
      acc = 0.f;
      c = 0;
      cur = g;
    }
    acc += h[(size_t)nn * HID + lane];
    ++c;
  }
  atomicAdd(&pool[(size_t)cur * HID + lane], acc);
  if (lane == 0) atomicAdd(&cnt[cur], c);
}

// ---------------- FC ---------------------------------------------------------
__global__ __launch_bounds__(64) void fc_kernel(const float* __restrict__ pool,
                                                const int* __restrict__ cnt,
                                                const float* __restrict__ Wfc,
                                                const float* __restrict__ bfc,
                                                float* __restrict__ out) {
  int g = blockIdx.x;
  int t = threadIdx.x;
  __shared__ float row[64];
  float inv = 1.0f / fmaxf((float)cnt[g], 1.0f);
  row[t] = pool[(size_t)g * HID + t] * inv;
  __syncthreads();
  if (t < NUM_CLASSES) {
    float acc = bfc[t];
#pragma unroll
    for (int k = 0; k < HID; ++k) acc += row[k] * Wfc[k * NUM_CLASSES + t];
    out[(size_t)g * NUM_CLASSES + t] = acc;
  }
}

// ---------------- launch -----------------------------------------------------
extern "C" void kernel_launch(void* const* d_in, const int* in_sizes, int n_in,
                              void* d_out, int out_size, void* d_ws, size_t ws_size,
                              hipStream_t stream) {
  const float* x = (const float*)d_in[0];
  const int* edge_index = (const int*)d_in[1];
  const int* batch = (const int*)d_in[2];
  const float* W1 = (const float*)d_in[3];
  const float* b1 = (const float*)d_in[4];
  const float* W2 = (const float*)d_in[5];
  const float* b2 = (const float*)d_in[6];
  const float* W3 = (const float*)d_in[7];
  const float* b3 = (const float*)d_in[8];
  const float* Wfc = (const float*)d_in[9];
  const float* bfc = (const float*)d_in[10];
  float* out = (float*)d_out;

  const int* src = edge_index;
  const int* dst = edge_index + N_EDGES;

  // workspace layout
  char* w = (char*)d_ws;
  float* h0 = (float*)w;                           // N*64 floats (25.6 MB)
  float* h1 = h0 + (size_t)N_NODES * HID;          // N*64 floats
  float* dinv = h1 + (size_t)N_NODES * HID;        // N floats
  int* row_ptr = (int*)(dinv + N_NODES);           // N+1 ints
  int* csr_src = row_ptr + (N_NODES + 1);          // E ints
  int* bucket_cnt = csr_src + N_EDGES;             // NBUCKET
  int* bucket_base = bucket_cnt + NBUCKET;         // NBUCKET+1
  int* bucket_cursor = bucket_base + NBUCKET + 1;  // NBUCKET
  float* pool = (float*)(bucket_cursor + NBUCKET); // 512*64 floats
  int* cnt = (int*)(pool + NUM_GRAPHS * HID);      // 512 ints
  int2* pair_buf = (int2*)h0;  // alias: pairs (25.6 MB) only live before GEMM1

  hipMemsetAsync(bucket_cnt, 0, NBUCKET * sizeof(int), stream);
  hipMemsetAsync(pool, 0, NUM_GRAPHS * HID * sizeof(float), stream);
  hipMemsetAsync(cnt, 0, NUM_GRAPHS * sizeof(int), stream);

  // CSR build
  bucket_hist_kernel<<<512, 256, 0, stream>>>(dst, bucket_cnt);
  bucket_scan_kernel<<<1, 64, 0, stream>>>(bucket_cnt, bucket_base, bucket_cursor,
                                           row_ptr);
  pair_scatter_kernel<<<512, 256, 0, stream>>>(src, dst, bucket_cursor, pair_buf);
  bucket_fill_kernel<<<NBUCKET, 256, 0, stream>>>(pair_buf, bucket_base, csr_src,
                                                  row_ptr, dinv);

  const int ggrid = (N_NODES + 63) / 64;
  const int agrid = (N_NODES + 3) / 4;

  // layer 1
  gemm_kernel<IN_DIM><<<ggrid, 256, 0, stream>>>(x, W1, dinv, h0, N_NODES);
  aggregate_kernel<<<agrid, 256, 0, stream>>>(h0, row_ptr, csr_src, dinv, b1, h1, 1);
  // layer 2
  gemm_kernel<HID><<<ggrid, 256, 0, stream>>>(h1, W2, dinv, h0, N_NODES);
  aggregate_kernel<<<agrid, 256, 0, stream>>>(h0, row_ptr, csr_src, dinv, b2, h1, 1);
  // layer 3
  gemm_kernel<HID><<<ggrid, 256, 0, stream>>>(h1, W3, dinv, h0, N_NODES);
  aggregate_kernel<<<agrid, 256, 0, stream>>>(h0, row_ptr, csr_src, dinv, b3, h1, 0);

  // pool + fc
  pool_kernel<<<512, 256, 0, stream>>>(h1, batch, pool, cnt);
  fc_kernel<<<NUM_GRAPHS, 64, 0, stream>>>(pool, cnt, Wfc, bfc, out);
}